// Round 8
// baseline (367.513 us; speedup 1.0000x reference)
//
#include <hip/hip_runtime.h>
#include <hip/hip_bf16.h>

typedef __bf16 bf16x8 __attribute__((ext_vector_type(8)));
typedef float  f32x4  __attribute__((ext_vector_type(4)));

// ---------- helpers ----------
static __device__ __forceinline__ unsigned short f2bf(float f) {
  unsigned int u = __float_as_uint(f);
  u += 0x7FFFu + ((u >> 16) & 1u);   // round-to-nearest-even
  return (unsigned short)(u >> 16);
}

static __device__ __forceinline__ void gl_lds16(const void* g, void* l) {
  __builtin_amdgcn_global_load_lds(
      (const __attribute__((address_space(1))) void*)g,
      (__attribute__((address_space(3))) void*)l,
      16, 0, 0);
}

// ---------- cast x: f32 -> bf16 ----------
__global__ __launch_bounds__(256) void cast_f32_bf16(
    const float* __restrict__ in, unsigned short* __restrict__ out, int n) {
  int i = (blockIdx.x * 256 + threadIdx.x) * 4;
  const int stride = gridDim.x * 256 * 4;
  for (; i < n; i += stride) {
    float4 f = *(const float4*)(in + i);
    ushort4 o;
    o.x = f2bf(f.x); o.y = f2bf(f.y); o.z = f2bf(f.z); o.w = f2bf(f.w);
    *(ushort4*)(out + i) = o;
  }
}

// ---------- transpose-cast W (1024x1024): wt[n][k] = w[k][n], f32 -> bf16 ----------
__global__ __launch_bounds__(256) void transpose_cast_w(
    const float* __restrict__ w, unsigned short* __restrict__ wt) {
  __shared__ float tile[16][17];
  const int tx = threadIdx.x & 15, ty = threadIdx.x >> 4;
  const int bx = blockIdx.x * 16, by = blockIdx.y * 16;
  tile[ty][tx] = w[(size_t)(by + ty) * 1024 + bx + tx];
  __syncthreads();
  wt[(size_t)(bx + ty) * 1024 + by + tx] = f2bf(tile[tx][ty]);
}

// ---------- 128x128-tile bf16 MFMA GEMM, BK=64, 2-phase counted-vmcnt dbuf ----------
// B given transposed ([N][K]). XCD-locality remap: d2 -> (ty=d2%gy, tx=d2/gy);
// gy%8==0 keeps A-row-panel sharers on one XCD. blockIdx.z batches.
// LDS 2 x 32 KiB buffers: per buffer A 16 KiB as [kk 0..1][row 0..127][64 B],
// B same. Staging = 16 consecutive rows x 64 B contiguous per wave-load
// (16 full cache lines); 64 B row stride on ds_read_b128 (conflict-neutral).
// K-loop (T3-minimum, m230/m248 recipe): per iter
//   STAGE(t+1 -> buf^1)   (8 gl_lds issued FIRST)
//   16x asm ds_read_b128 from buf (no mem clobber -> no compiler drains)
//   lgkmcnt(0) + sched_barrier   (rule #18)
//   setprio(1) 32 MFMA setprio(0)
//   vmcnt(0)              <- stage waited only AFTER ~400cy of reads+MFMA
//   s_barrier
// vs r7 (__syncthreads right after STAGE = full latency exposed per K-step).
// Safety: reads of buf[t&1] retire at lgkmcnt(0) before end-of-iter barrier;
// overwrite of that buffer lands by the NEXT iter's vmcnt(0).
// MODE 3: fused-QKV split write (Cv = qb base; kb = +16Mi elems, vt = +32Mi)
// MODE 4: scores + fused exp + per-block partial row-sums
// MODE 5: PV + row rescale by aux[z*2048+row]
template <int MODE>
__global__ __launch_bounds__(256, 2) void gemm_bt(
    const unsigned short* __restrict__ A, int lda, size_t astride,
    const unsigned short* __restrict__ B, int ldb, size_t bstride,
    int K, void* __restrict__ Cv, int ldc, size_t cstride,
    float* __restrict__ aux) {
  __shared__ __align__(16) unsigned char lds[65536];  // 2 x (A 16K | B 16K)
  const unsigned d2 = blockIdx.x + gridDim.x * blockIdx.y;
  const unsigned ty = d2 % gridDim.y;
  const unsigned tx = d2 / gridDim.y;
  const int bn0 = tx * 128;
  const int bm0 = ty * 128;
  A += (size_t)blockIdx.z * astride;
  B += (size_t)blockIdx.z * bstride;

  const int tid = threadIdx.x;
  const int wid = tid >> 6, lane = tid & 63;
  const int wr = wid >> 1, wc = wid & 1;
  const int l15 = lane & 15, kq = lane >> 4;

  // staging: chunk c = j*256 + tid -> kk = j>>1, row = (j&1)*64 + tid>>2,
  // sub-16B = tid&3. LDS dest byte = c*16 (linear, wave-uniform base + lane*16).
  const int sr = tid >> 2;
  const int ssub = (tid & 3) * 8;
  size_t aoff[4], boff[4];
#pragma unroll
  for (int j = 0; j < 4; ++j) {
    const int r = (j & 1) * 64 + sr;
    const int kko = (j >> 1) * 32;
    aoff[j] = (size_t)(bm0 + r) * lda + kko + ssub;
    boff[j] = (size_t)(bn0 + r) * ldb + kko + ssub;
  }

#define STAGE(t) do { \
    unsigned char* bufA_ = lds + ((t) & 1) * 32768 + wid * 1024; \
    unsigned char* bufB_ = bufA_ + 16384; \
    const int kc_ = (t) << 6; \
    _Pragma("unroll") \
    for (int j = 0; j < 4; ++j) { \
      gl_lds16(A + aoff[j] + kc_, bufA_ + j * 4096); \
      gl_lds16(B + boff[j] + kc_, bufB_ + j * 4096); \
    } \
  } while (0)
#define DSR(dst, addr) asm volatile("ds_read_b128 %0, %1" : "=v"(dst) : "v"(addr))

  // LDS byte-address bases for asm ds_read_b128
  const unsigned ldsbase =
      (unsigned)(unsigned long long)(__attribute__((address_space(3))) unsigned char*)lds;
  const unsigned aA = ldsbase + (wr * 64 + l15) * 64 + kq * 16;            // + kk*8192 + mi*1024
  const unsigned aB = ldsbase + 16384 + (wc * 64 + l15) * 64 + kq * 16;    // + kk*8192 + ni*1024

  f32x4 acc[4][4] = {};
  const int nkt = K >> 6;

  STAGE(0);
  asm volatile("s_waitcnt vmcnt(0)" ::: "memory");
  __builtin_amdgcn_s_barrier();

  for (int t = 0; t < nkt; ++t) {
    if (t + 1 < nkt) STAGE(t + 1);          // issue early...
    const unsigned bofs = (unsigned)(t & 1) * 32768u;

    bf16x8 af[2][4], bg[2][4];
#pragma unroll
    for (int kk = 0; kk < 2; ++kk) {
#pragma unroll
      for (int mi = 0; mi < 4; ++mi) DSR(af[kk][mi], bofs + aA + kk * 8192 + mi * 1024);
#pragma unroll
      for (int ni = 0; ni < 4; ++ni) DSR(bg[kk][ni], bofs + aB + kk * 8192 + ni * 1024);
    }
    asm volatile("s_waitcnt lgkmcnt(0)" ::: "memory");
    __builtin_amdgcn_sched_barrier(0);
    __builtin_amdgcn_s_setprio(1);
#pragma unroll
    for (int kk = 0; kk < 2; ++kk)
#pragma unroll
      for (int mi = 0; mi < 4; ++mi)
#pragma unroll
        for (int ni = 0; ni < 4; ++ni)
          acc[mi][ni] = __builtin_amdgcn_mfma_f32_16x16x32_bf16(af[kk][mi], bg[kk][ni], acc[mi][ni], 0, 0, 0);
    __builtin_amdgcn_s_setprio(0);
    asm volatile("s_waitcnt vmcnt(0)" ::: "memory");   // ...wait late (hidden)
    __builtin_amdgcn_s_barrier();
  }
#undef STAGE
#undef DSR

  // epilogue: C/D layout col = lane&15, row = (lane>>4)*4 + reg  [verified m89/m91]
  if constexpr (MODE == 3) {
#pragma unroll
    for (int mi = 0; mi < 4; ++mi)
#pragma unroll
      for (int ni = 0; ni < 4; ++ni)
#pragma unroll
        for (int r = 0; r < 4; ++r) {
          const int row = bm0 + wr * 64 + mi * 16 + kq * 4 + r;
          const int col = bn0 + wc * 64 + ni * 16 + l15;
          const float v = acc[mi][ni][r];
          unsigned short* q = (unsigned short*)Cv;
          if (col < 1024) {
            q[(size_t)row * 1024 + col] = f2bf(v);
          } else if (col < 2048) {
            q[16777216u + (size_t)row * 1024 + (col - 1024)] = f2bf(v);
          } else {
            const int b = row >> 11, s = row & 2047;
            q[33554432u + ((size_t)(b * 1024 + (col - 2048))) * 2048 + s] = f2bf(v);
          }
        }
  } else if constexpr (MODE == 4) {
    __shared__ float redsm[128][2];
    unsigned short* pp = (unsigned short*)Cv + (size_t)blockIdx.z * cstride;
    float rs[4][4];
#pragma unroll
    for (int mi = 0; mi < 4; ++mi)
#pragma unroll
      for (int r = 0; r < 4; ++r) rs[mi][r] = 0.f;
#pragma unroll
    for (int mi = 0; mi < 4; ++mi)
#pragma unroll
      for (int ni = 0; ni < 4; ++ni)
#pragma unroll
        for (int r = 0; r < 4; ++r) {
          // exp(acc/32) = 2^(acc * log2(e)/32)
          const float e = exp2f(acc[mi][ni][r] * 0.045084220027780106f);
          rs[mi][r] += e;
          const int row = bm0 + wr * 64 + mi * 16 + kq * 4 + r;
          const int col = bn0 + wc * 64 + ni * 16 + l15;
          pp[(size_t)row * ldc + col] = f2bf(e);
        }
    // reduce each row's 64-col wave partial over the 16 l15 lanes
#pragma unroll
    for (int mi = 0; mi < 4; ++mi)
#pragma unroll
      for (int r = 0; r < 4; ++r) {
        float s = rs[mi][r];
        s += __shfl_xor(s, 1); s += __shfl_xor(s, 2);
        s += __shfl_xor(s, 4); s += __shfl_xor(s, 8);
        rs[mi][r] = s;
      }
    if (l15 == 0) {
#pragma unroll
      for (int mi = 0; mi < 4; ++mi)
#pragma unroll
        for (int r = 0; r < 4; ++r)
          redsm[wr * 64 + mi * 16 + kq * 4 + r][wc] = rs[mi][r];
    }
    __syncthreads();
    if (tid < 128)
      aux[((size_t)blockIdx.z * 16 + tx) * 2048 + bm0 + tid] =
          redsm[tid][0] + redsm[tid][1];
  } else {  // MODE 5
    const float* inv = aux + (size_t)blockIdx.z * 2048;
    float* op = (float*)Cv + (size_t)blockIdx.z * cstride;
#pragma unroll
    for (int mi = 0; mi < 4; ++mi)
#pragma unroll
      for (int r = 0; r < 4; ++r) {
        const int row = bm0 + wr * 64 + mi * 16 + kq * 4 + r;
        const float iv = inv[row];
#pragma unroll
        for (int ni = 0; ni < 4; ++ni) {
          const int col = bn0 + wc * 64 + ni * 16 + l15;
          op[(size_t)row * ldc + col] = acc[mi][ni][r] * iv;
        }
      }
  }
}

// ---------- combine partial row-sums -> inv[row] (deterministic order) ----------
__global__ __launch_bounds__(256) void combine_inv(
    const float* __restrict__ part, float* __restrict__ inv, int n) {
  const int i = blockIdx.x * 256 + threadIdx.x;
  if (i >= n) return;            // n = g*2048
  const int z = i >> 11, row = i & 2047;
  const float* p = part + ((size_t)z * 16) * 2048 + row;
  float s = 0.f;
#pragma unroll
  for (int j = 0; j < 16; ++j) s += p[j * 2048];
  inv[i] = 1.0f / s;
}

// ---------- launch ----------
extern "C" void kernel_launch(void* const* d_in, const int* in_sizes, int n_in,
                              void* d_out, int out_size, void* d_ws, size_t ws_size,
                              hipStream_t stream) {
  const float* x  = (const float*)d_in[0];
  const float* Wq = (const float*)d_in[1];
  const float* Wk = (const float*)d_in[2];
  const float* Wv = (const float*)d_in[3];
  float* out = (float*)d_out;
  char* ws = (char*)d_ws;

  // workspace layout (bytes)
  unsigned short* xb     = (unsigned short*)ws;                  // 33.5 MB (dead after QKV)
  unsigned short* wt_all = (unsigned short*)(ws + 33554432);     // 6 MB: WqT|WkT|WvT [3072][1024]
  unsigned short* qb     = (unsigned short*)(ws + 39845888);     // 33.5 MB
  unsigned short* kb     = qb + 16777216;                        // 33.5 MB
  unsigned short* vt     = kb + 16777216;                        // 33.5 MB (vT: [b*1024+e][s])
  const size_t off_scores = 140509184ull;                        // end of vt

  // per-batch attention scratch: P' bf16 8 MiB + part 128 KiB + inv 8 KiB
  const size_t per_b = 8388608ull + 131072ull + 8192ull;
  int G; char *pPc, *partc, *invc;
  const size_t avail = ws_size > off_scores ? ws_size - off_scores : 0;
  G = (int)(avail / per_b); if (G > 8) G = 8;
  if (G >= 1) {
    pPc   = ws + off_scores;
    partc = pPc + (size_t)G * 8388608ull;
    invc  = partc + (size_t)G * 131072ull;
  } else {
    G = 2;  // fallback: reuse xb region (33.5 MB >= 2 x 8.53 MB); xb dead after QKV
    pPc   = ws;
    partc = ws + 2 * 8388608ull;
    invc  = partc + 2 * 131072ull;
  }

  cast_f32_bf16<<<2048, 256, 0, stream>>>(x, xb, 16384 * 1024);
  transpose_cast_w<<<dim3(64, 64), 256, 0, stream>>>(Wq, wt_all);
  transpose_cast_w<<<dim3(64, 64), 256, 0, stream>>>(Wk, wt_all + 1048576);
  transpose_cast_w<<<dim3(64, 64), 256, 0, stream>>>(Wv, wt_all + 2097152);

  // fused QKV projection: M=16384, N=3072, K=1024
  gemm_bt<3><<<dim3(24, 128), 256, 0, stream>>>(xb, 1024, 0, wt_all, 1024, 0,
                                                1024, qb, 0, 0, nullptr);

  for (int b0 = 0; b0 < 8; b0 += G) {
    const int g = (8 - b0) < G ? (8 - b0) : G;
    const size_t so = (size_t)b0 * 2097152;  // q/k/v/out batch offset (elems)
    // P' = exp(q.k^T/32) bf16 + partial row sums: M=N=2048, K=1024
    gemm_bt<4><<<dim3(16, 16, g), 256, 0, stream>>>(
        qb + so, 1024, 2097152, kb + so, 1024, 2097152, 1024,
        (unsigned short*)pPc, 2048, 4194304, (float*)partc);
    // inv[row] = 1 / sum_row  (deterministic 16-partial combine)
    combine_inv<<<(g * 2048 + 255) / 256, 256, 0, stream>>>(
        (const float*)partc, (float*)invc, g * 2048);
    // out = (P'.v) * inv : A=P' [2048][2048] bf16, B^T = vT_b [1024][2048], K=2048
    gemm_bt<5><<<dim3(8, 16, g), 256, 0, stream>>>(
        (const unsigned short*)pPc, 2048, 4194304,
        vt + so, 2048, 2097152, 2048,
        out + so, 1024, 2097152, (float*)invc);
  }
}

// Round 9
// 363.471 us; speedup vs baseline: 1.0111x; 1.0111x over previous
//
#include <hip/hip_runtime.h>
#include <hip/hip_bf16.h>

typedef __bf16 bf16x8 __attribute__((ext_vector_type(8)));
typedef float  f32x4  __attribute__((ext_vector_type(4)));

// ---------- helpers ----------
static __device__ __forceinline__ unsigned short f2bf(float f) {
  unsigned int u = __float_as_uint(f);
  u += 0x7FFFu + ((u >> 16) & 1u);   // round-to-nearest-even
  return (unsigned short)(u >> 16);
}

static __device__ __forceinline__ void gl_lds16(const void* g, void* l) {
  __builtin_amdgcn_global_load_lds(
      (const __attribute__((address_space(1))) void*)g,
      (__attribute__((address_space(3))) void*)l,
      16, 0, 0);
}

// ---------- cast x: f32 -> bf16 ----------
__global__ __launch_bounds__(256) void cast_f32_bf16(
    const float* __restrict__ in, unsigned short* __restrict__ out, int n) {
  int i = (blockIdx.x * 256 + threadIdx.x) * 4;
  const int stride = gridDim.x * 256 * 4;
  for (; i < n; i += stride) {
    float4 f = *(const float4*)(in + i);
    ushort4 o;
    o.x = f2bf(f.x); o.y = f2bf(f.y); o.z = f2bf(f.z); o.w = f2bf(f.w);
    *(ushort4*)(out + i) = o;
  }
}

// ---------- transpose-cast W (1024x1024): wt[n][k] = w[k][n], f32 -> bf16 ----------
__global__ __launch_bounds__(256) void transpose_cast_w(
    const float* __restrict__ w, unsigned short* __restrict__ wt) {
  __shared__ float tile[16][17];
  const int tx = threadIdx.x & 15, ty = threadIdx.x >> 4;
  const int bx = blockIdx.x * 16, by = blockIdx.y * 16;
  tile[ty][tx] = w[(size_t)(by + ty) * 1024 + bx + tx];
  __syncthreads();
  wt[(size_t)(bx + ty) * 1024 + by + tx] = f2bf(tile[tx][ty]);
}

// ---------- 128x128-tile bf16 MFMA GEMM, BK=32, TRIPLE-buffer counted-vmcnt ----------
// B given transposed ([N][K]). XCD-locality remap: d2 -> (ty=d2%gy, tx=d2/gy);
// gy%8==0 keeps A-row-panel sharers on one XCD. blockIdx.z batches.
// LDS 3 x 16 KiB slots (A 8K [row 0..127][32e=64B] | B 8K same). 48 KB total
// keeps 3 blocks/CU (r7's occupancy) while giving r8's issue-early/wait-late:
//   iter t: vmcnt(4) [stage t landed, t+1 in flight] ; s_barrier ;
//           8x asm ds_read_b128 from slot t%3 ; STAGE(t+2 -> slot (t+2)%3) ;
//           lgkmcnt(0)+sched_barrier ; setprio(1) 16 MFMA setprio(0)
// Stage cover = ~2 full iters (issue at t, wait at t+2 top) >= L2/HBM latency.
// W-A-R: slot (t+2)%3 last read in iter t-1; reads retire at that iter's
// lgkmcnt(0), before every wave reaches iter t's barrier; overwrite issued
// after the barrier. asm ds_reads carry no mem clobber so the compiler can't
// alias them vs staging and re-insert vmcnt drains (r3/r4 failure).
// MODE 3: fused-QKV split write (Cv = qb base; kb = +16Mi elems, vt = +32Mi)
// MODE 4: scores + fused exp + per-block partial row-sums
// MODE 5: PV + row rescale by aux[z*2048+row]
template <int MODE>
__global__ __launch_bounds__(256, 2) void gemm_bt(
    const unsigned short* __restrict__ A, int lda, size_t astride,
    const unsigned short* __restrict__ B, int ldb, size_t bstride,
    int K, void* __restrict__ Cv, int ldc, size_t cstride,
    float* __restrict__ aux) {
  __shared__ __align__(16) unsigned char lds[49152];  // 3 x (A 8K | B 8K)
  const unsigned d2 = blockIdx.x + gridDim.x * blockIdx.y;
  const unsigned ty = d2 % gridDim.y;
  const unsigned tx = d2 / gridDim.y;
  const int bn0 = tx * 128;
  const int bm0 = ty * 128;
  A += (size_t)blockIdx.z * astride;
  B += (size_t)blockIdx.z * bstride;

  const int tid = threadIdx.x;
  const int wid = tid >> 6, lane = tid & 63;
  const int wr = wid >> 1, wc = wid & 1;
  const int l15 = lane & 15, kq = lane >> 4;

  // staging (r2-proven): element e = wid*512 + lane*8 -> (row e>>5, col e&31);
  // chunks at rows r0 and r0+64. Contiguous 64 B per 4 lanes (full cache lines).
  const int e0 = wid * 512 + lane * 8;
  const int r0 = e0 >> 5, c0 = e0 & 31;
  const size_t aoff0 = (size_t)(bm0 + r0) * lda + c0;
  const size_t aoff1 = (size_t)(bm0 + r0 + 64) * lda + c0;
  const size_t boff0 = (size_t)(bn0 + r0) * ldb + c0;
  const size_t boff1 = (size_t)(bn0 + r0 + 64) * ldb + c0;

#define STAGE(t) do { \
    unsigned char* s_ = lds + ((t) % 3) * 16384 + wid * 1024; \
    const int kc_ = (t) << 5; \
    gl_lds16(A + aoff0 + kc_, s_); \
    gl_lds16(A + aoff1 + kc_, s_ + 4096); \
    gl_lds16(B + boff0 + kc_, s_ + 8192); \
    gl_lds16(B + boff1 + kc_, s_ + 12288); \
  } while (0)
#define DSR(dst, addr) asm volatile("ds_read_b128 %0, %1" : "=v"(dst) : "v"(addr))

  // LDS byte-address bases for asm ds_read_b128
  const unsigned ldsbase =
      (unsigned)(unsigned long long)(__attribute__((address_space(3))) unsigned char*)lds;
  const unsigned aA = ldsbase + (wr * 64 + l15) * 64 + kq * 16;          // + slot + mi*1024
  const unsigned aB = ldsbase + 8192 + (wc * 64 + l15) * 64 + kq * 16;   // + slot + ni*1024

  f32x4 acc[4][4] = {};
  const int nkt = K >> 5;

  STAGE(0);
  STAGE(1);

  for (int t = 0; t < nkt; ++t) {
    if (t < nkt - 1) asm volatile("s_waitcnt vmcnt(4)" ::: "memory");
    else             asm volatile("s_waitcnt vmcnt(0)" ::: "memory");
    __builtin_amdgcn_s_barrier();   // all waves' stage-t landed; slot (t+2)%3 readers done

    const unsigned so = (unsigned)(t % 3) * 16384u;
    bf16x8 af[4], bg[4];
#pragma unroll
    for (int mi = 0; mi < 4; ++mi) DSR(af[mi], so + aA + mi * 1024);
#pragma unroll
    for (int ni = 0; ni < 4; ++ni) DSR(bg[ni], so + aB + ni * 1024);

    if (t + 2 < nkt) STAGE(t + 2);  // issue 2 ahead; waited at iter t+2 top

    asm volatile("s_waitcnt lgkmcnt(0)" ::: "memory");
    __builtin_amdgcn_sched_barrier(0);
    __builtin_amdgcn_s_setprio(1);
#pragma unroll
    for (int mi = 0; mi < 4; ++mi)
#pragma unroll
      for (int ni = 0; ni < 4; ++ni)
        acc[mi][ni] = __builtin_amdgcn_mfma_f32_16x16x32_bf16(af[mi], bg[ni], acc[mi][ni], 0, 0, 0);
    __builtin_amdgcn_s_setprio(0);
  }
#undef STAGE
#undef DSR

  // epilogue: C/D layout col = lane&15, row = (lane>>4)*4 + reg  [verified m89/m91]
  if constexpr (MODE == 3) {
#pragma unroll
    for (int mi = 0; mi < 4; ++mi)
#pragma unroll
      for (int ni = 0; ni < 4; ++ni)
#pragma unroll
        for (int r = 0; r < 4; ++r) {
          const int row = bm0 + wr * 64 + mi * 16 + kq * 4 + r;
          const int col = bn0 + wc * 64 + ni * 16 + l15;
          const float v = acc[mi][ni][r];
          unsigned short* q = (unsigned short*)Cv;
          if (col < 1024) {
            q[(size_t)row * 1024 + col] = f2bf(v);
          } else if (col < 2048) {
            q[16777216u + (size_t)row * 1024 + (col - 1024)] = f2bf(v);
          } else {
            const int b = row >> 11, s = row & 2047;
            q[33554432u + ((size_t)(b * 1024 + (col - 2048))) * 2048 + s] = f2bf(v);
          }
        }
  } else if constexpr (MODE == 4) {
    __shared__ float redsm[128][2];
    unsigned short* pp = (unsigned short*)Cv + (size_t)blockIdx.z * cstride;
    float rs[4][4];
#pragma unroll
    for (int mi = 0; mi < 4; ++mi)
#pragma unroll
      for (int r = 0; r < 4; ++r) rs[mi][r] = 0.f;
#pragma unroll
    for (int mi = 0; mi < 4; ++mi)
#pragma unroll
      for (int ni = 0; ni < 4; ++ni)
#pragma unroll
        for (int r = 0; r < 4; ++r) {
          // exp(acc/32) = 2^(acc * log2(e)/32)
          const float e = exp2f(acc[mi][ni][r] * 0.045084220027780106f);
          rs[mi][r] += e;
          const int row = bm0 + wr * 64 + mi * 16 + kq * 4 + r;
          const int col = bn0 + wc * 64 + ni * 16 + l15;
          pp[(size_t)row * ldc + col] = f2bf(e);
        }
    // reduce each row's 64-col wave partial over the 16 l15 lanes
#pragma unroll
    for (int mi = 0; mi < 4; ++mi)
#pragma unroll
      for (int r = 0; r < 4; ++r) {
        float s = rs[mi][r];
        s += __shfl_xor(s, 1); s += __shfl_xor(s, 2);
        s += __shfl_xor(s, 4); s += __shfl_xor(s, 8);
        rs[mi][r] = s;
      }
    if (l15 == 0) {
#pragma unroll
      for (int mi = 0; mi < 4; ++mi)
#pragma unroll
        for (int r = 0; r < 4; ++r)
          redsm[wr * 64 + mi * 16 + kq * 4 + r][wc] = rs[mi][r];
    }
    __syncthreads();
    if (tid < 128)
      aux[((size_t)blockIdx.z * 16 + tx) * 2048 + bm0 + tid] =
          redsm[tid][0] + redsm[tid][1];
  } else {  // MODE 5
    const float* inv = aux + (size_t)blockIdx.z * 2048;
    float* op = (float*)Cv + (size_t)blockIdx.z * cstride;
#pragma unroll
    for (int mi = 0; mi < 4; ++mi)
#pragma unroll
      for (int r = 0; r < 4; ++r) {
        const int row = bm0 + wr * 64 + mi * 16 + kq * 4 + r;
        const float iv = inv[row];
#pragma unroll
        for (int ni = 0; ni < 4; ++ni) {
          const int col = bn0 + wc * 64 + ni * 16 + l15;
          op[(size_t)row * ldc + col] = acc[mi][ni][r] * iv;
        }
      }
  }
}

// ---------- combine partial row-sums -> inv[row] (deterministic order) ----------
__global__ __launch_bounds__(256) void combine_inv(
    const float* __restrict__ part, float* __restrict__ inv, int n) {
  const int i = blockIdx.x * 256 + threadIdx.x;
  if (i >= n) return;            // n = g*2048
  const int z = i >> 11, row = i & 2047;
  const float* p = part + ((size_t)z * 16) * 2048 + row;
  float s = 0.f;
#pragma unroll
  for (int j = 0; j < 16; ++j) s += p[j * 2048];
  inv[i] = 1.0f / s;
}

// ---------- launch ----------
extern "C" void kernel_launch(void* const* d_in, const int* in_sizes, int n_in,
                              void* d_out, int out_size, void* d_ws, size_t ws_size,
                              hipStream_t stream) {
  const float* x  = (const float*)d_in[0];
  const float* Wq = (const float*)d_in[1];
  const float* Wk = (const float*)d_in[2];
  const float* Wv = (const float*)d_in[3];
  float* out = (float*)d_out;
  char* ws = (char*)d_ws;

  // workspace layout (bytes)
  unsigned short* xb     = (unsigned short*)ws;                  // 33.5 MB (dead after QKV)
  unsigned short* wt_all = (unsigned short*)(ws + 33554432);     // 6 MB: WqT|WkT|WvT [3072][1024]
  unsigned short* qb     = (unsigned short*)(ws + 39845888);     // 33.5 MB
  unsigned short* kb     = qb + 16777216;                        // 33.5 MB
  unsigned short* vt     = kb + 16777216;                        // 33.5 MB (vT: [b*1024+e][s])
  const size_t off_scores = 140509184ull;                        // end of vt

  // per-batch attention scratch: P' bf16 8 MiB + part 128 KiB + inv 8 KiB
  const size_t per_b = 8388608ull + 131072ull + 8192ull;
  int G; char *pPc, *partc, *invc;
  const size_t avail = ws_size > off_scores ? ws_size - off_scores : 0;
  G = (int)(avail / per_b); if (G > 8) G = 8;
  if (G >= 1) {
    pPc   = ws + off_scores;
    partc = pPc + (size_t)G * 8388608ull;
    invc  = partc + (size_t)G * 131072ull;
  } else {
    G = 2;  // fallback: reuse xb region (33.5 MB >= 2 x 8.53 MB); xb dead after QKV
    pPc   = ws;
    partc = ws + 2 * 8388608ull;
    invc  = partc + 2 * 131072ull;
  }

  cast_f32_bf16<<<2048, 256, 0, stream>>>(x, xb, 16384 * 1024);
  transpose_cast_w<<<dim3(64, 64), 256, 0, stream>>>(Wq, wt_all);
  transpose_cast_w<<<dim3(64, 64), 256, 0, stream>>>(Wk, wt_all + 1048576);
  transpose_cast_w<<<dim3(64, 64), 256, 0, stream>>>(Wv, wt_all + 2097152);

  // fused QKV projection: M=16384, N=3072, K=1024
  gemm_bt<3><<<dim3(24, 128), 256, 0, stream>>>(xb, 1024, 0, wt_all, 1024, 0,
                                                1024, qb, 0, 0, nullptr);

  for (int b0 = 0; b0 < 8; b0 += G) {
    const int g = (8 - b0) < G ? (8 - b0) : G;
    const size_t so = (size_t)b0 * 2097152;  // q/k/v/out batch offset (elems)
    // P' = exp(q.k^T/32) bf16 + partial row sums: M=N=2048, K=1024
    gemm_bt<4><<<dim3(16, 16, g), 256, 0, stream>>>(
        qb + so, 1024, 2097152, kb + so, 1024, 2097152, 1024,
        (unsigned short*)pPc, 2048, 4194304, (float*)partc);
    // inv[row] = 1 / sum_row  (deterministic 16-partial combine)
    combine_inv<<<(g * 2048 + 255) / 256, 256, 0, stream>>>(
        (const float*)partc, (float*)invc, g * 2048);
    // out = (P'.v) * inv : A=P' [2048][2048] bf16, B^T = vT_b [1024][2048], K=2048
    gemm_bt<5><<<dim3(8, 16, g), 256, 0, stream>>>(
        (const unsigned short*)pPc, 2048, 4194304,
        vt + so, 2048, 2097152, 2048,
        out + so, 1024, 2097152, (float*)invc);
  }
}

// Round 10
// 362.544 us; speedup vs baseline: 1.0137x; 1.0026x over previous
//
#include <hip/hip_runtime.h>
#include <hip/hip_bf16.h>

typedef __bf16 bf16x8 __attribute__((ext_vector_type(8)));
typedef float  f32x4  __attribute__((ext_vector_type(4)));

// ---------- helpers ----------
static __device__ __forceinline__ unsigned short f2bf(float f) {
  unsigned int u = __float_as_uint(f);
  u += 0x7FFFu + ((u >> 16) & 1u);   // round-to-nearest-even
  return (unsigned short)(u >> 16);
}

static __device__ __forceinline__ void gl_lds16(const void* g, void* l) {
  __builtin_amdgcn_global_load_lds(
      (const __attribute__((address_space(1))) void*)g,
      (__attribute__((address_space(3))) void*)l,
      16, 0, 0);
}

// ---------- cast x: f32 -> bf16 ----------
__global__ __launch_bounds__(256) void cast_f32_bf16(
    const float* __restrict__ in, unsigned short* __restrict__ out, int n) {
  int i = (blockIdx.x * 256 + threadIdx.x) * 4;
  const int stride = gridDim.x * 256 * 4;
  for (; i < n; i += stride) {
    float4 f = *(const float4*)(in + i);
    ushort4 o;
    o.x = f2bf(f.x); o.y = f2bf(f.y); o.z = f2bf(f.z); o.w = f2bf(f.w);
    *(ushort4*)(out + i) = o;
  }
}

// ---------- transpose-cast Wq|Wk|Wv in one launch (z picks the matrix) ----------
__global__ __launch_bounds__(256) void transpose_cast_w3(
    const float* __restrict__ w0, const float* __restrict__ w1,
    const float* __restrict__ w2, unsigned short* __restrict__ wt) {
  __shared__ float tile[16][17];
  const float* w = blockIdx.z == 0 ? w0 : (blockIdx.z == 1 ? w1 : w2);
  unsigned short* o = wt + (size_t)blockIdx.z * 1048576;
  const int tx = threadIdx.x & 15, ty = threadIdx.x >> 4;
  const int bx = blockIdx.x * 16, by = blockIdx.y * 16;
  tile[ty][tx] = w[(size_t)(by + ty) * 1024 + bx + tx];
  __syncthreads();
  o[(size_t)(bx + ty) * 1024 + by + tx] = f2bf(tile[tx][ty]);
}

// ---------- 256x256-tile bf16 GEMM, BK=32, SINGLE 32 KB buffer, r7 schedule ----------
// QKV only. 8 waves (2M x 4N), 512 threads; LDS 32 KB -> 3-4 blocks/CU
// (24-32 waves/CU vs 128-tile's 12) AND 2x better staging-bytes/MFMA.
// Staging (r2-proven): chunk c = j*512+tid -> row c>>2, sub (tid&3)*16B;
// each wave-load = 16 consecutive rows x 64 B contiguous; LDS dest linear.
// 64 B LDS rows: 8 lanes/bank-quad on ds_read = BW-minimum (r2-measured ~0).
// MODE 3 fused-QKV split write (Cv = qb base; kb = +16Mi elems, vt = +32Mi).
__global__ __launch_bounds__(512, 2) void gemm256s(
    const unsigned short* __restrict__ A, int lda,
    const unsigned short* __restrict__ B, int ldb,
    int K, void* __restrict__ Cv) {
  __shared__ __align__(16) unsigned char lds[32768];  // A 16K | B 16K
  const unsigned d2 = blockIdx.x + gridDim.x * blockIdx.y;
  const unsigned ty = d2 % gridDim.y;      // gy % 8 == 0 -> A-panel XCD-local
  const unsigned tx = d2 / gridDim.y;
  const int bm0 = ty * 256;
  const int bn0 = tx * 256;

  const int tid = threadIdx.x;
  const int wid = tid >> 6, lane = tid & 63;
  const int wr = wid >> 2, wc = wid & 3;   // wave grid 2(M) x 4(N)
  const int l15 = lane & 15, kq = lane >> 4;

  // staging: chunk c = j*512 + tid -> row = c>>2 (64 B rows), sub = (tid&3)*16B
  const size_t aoff0 = (size_t)(bm0 + (tid >> 2)) * lda + (tid & 3) * 8;
  const size_t aoff1 = aoff0 + (size_t)128 * lda;
  const size_t boff0 = (size_t)(bn0 + (tid >> 2)) * ldb + (tid & 3) * 8;
  const size_t boff1 = boff0 + (size_t)128 * ldb;
  unsigned char* dA0 = lds + wid * 1024;
  unsigned char* dA1 = lds + 8192 + wid * 1024;
  unsigned char* dB0 = lds + 16384 + wid * 1024;
  unsigned char* dB1 = lds + 24576 + wid * 1024;

  f32x4 acc[8][4] = {};
  const int nkt = K >> 5;
  for (int kt = 0; kt < nkt; ++kt) {
    const int kc = kt << 5;
    gl_lds16(A + aoff0 + kc, dA0);
    gl_lds16(A + aoff1 + kc, dA1);
    gl_lds16(B + boff0 + kc, dB0);
    gl_lds16(B + boff1 + kc, dB1);
    __syncthreads();

    bf16x8 af[8], bg[4];
#pragma unroll
    for (int mi = 0; mi < 8; ++mi)
      af[mi] = *(const bf16x8*)(lds + (wr * 128 + mi * 16 + l15) * 64 + kq * 16);
#pragma unroll
    for (int ni = 0; ni < 4; ++ni)
      bg[ni] = *(const bf16x8*)(lds + 16384 + (wc * 64 + ni * 16 + l15) * 64 + kq * 16);
#pragma unroll
    for (int mi = 0; mi < 8; ++mi)
#pragma unroll
      for (int ni = 0; ni < 4; ++ni)
        acc[mi][ni] = __builtin_amdgcn_mfma_f32_16x16x32_bf16(af[mi], bg[ni], acc[mi][ni], 0, 0, 0);
    __syncthreads();
  }

  // epilogue: C/D layout col = lane&15, row = (lane>>4)*4 + reg
#pragma unroll
  for (int mi = 0; mi < 8; ++mi)
#pragma unroll
    for (int ni = 0; ni < 4; ++ni)
#pragma unroll
      for (int r = 0; r < 4; ++r) {
        const int row = bm0 + wr * 128 + mi * 16 + kq * 4 + r;
        const int col = bn0 + wc * 64 + ni * 16 + l15;
        const float v = acc[mi][ni][r];
        unsigned short* q = (unsigned short*)Cv;
        if (col < 1024) {
          q[(size_t)row * 1024 + col] = f2bf(v);
        } else if (col < 2048) {
          q[16777216u + (size_t)row * 1024 + (col - 1024)] = f2bf(v);
        } else {
          const int b = row >> 11, s = row & 2047;
          q[33554432u + ((size_t)(b * 1024 + (col - 2048))) * 2048 + s] = f2bf(v);
        }
      }
}

// ---------- 128x128-tile bf16 MFMA GEMM, BK=64 single buffer (r7 = best) ----------
// MODE 4: scores + fused exp + per-block partial row-sums -> aux[(z*16+tx)*2048+row]
// MODE 5: PV; inv computed IN-BLOCK from the 16 partials (combine kernel folded)
template <int MODE>
__global__ __launch_bounds__(256, 2) void gemm_bt(
    const unsigned short* __restrict__ A, int lda, size_t astride,
    const unsigned short* __restrict__ B, int ldb, size_t bstride,
    int K, void* __restrict__ Cv, int ldc, size_t cstride,
    float* __restrict__ aux) {
  __shared__ __align__(16) unsigned char lds[32768];  // A 16K | B 16K
  __shared__ float smInv[128];
  const unsigned d2 = blockIdx.x + gridDim.x * blockIdx.y;
  const unsigned ty = d2 % gridDim.y;
  const unsigned tx = d2 / gridDim.y;
  const int bn0 = tx * 128;
  const int bm0 = ty * 128;
  A += (size_t)blockIdx.z * astride;
  B += (size_t)blockIdx.z * bstride;

  const int tid = threadIdx.x;
  const int wid = tid >> 6, lane = tid & 63;
  const int wr = wid >> 1, wc = wid & 1;
  const int l15 = lane & 15, kq = lane >> 4;

  if constexpr (MODE == 5) {  // inv[row] for this block's 128 rows
    if (tid < 128) {
      const float* p = aux + (size_t)blockIdx.z * 32768 + bm0 + tid;
      float s = 0.f;
#pragma unroll
      for (int j = 0; j < 16; ++j) s += p[j * 2048];
      smInv[tid] = 1.0f / s;   // visible after iter-0 __syncthreads
    }
  }

  // staging: chunk c = j*256 + tid -> kk = j>>1, row = (j&1)*64 + tid>>2, sub = tid&3
  const int sr = tid >> 2;
  const int ssub = (tid & 3) * 8;
  size_t aoff[4], boff[4];
#pragma unroll
  for (int j = 0; j < 4; ++j) {
    const int r = (j & 1) * 64 + sr;
    const int kko = (j >> 1) * 32;
    aoff[j] = (size_t)(bm0 + r) * lda + kko + ssub;
    boff[j] = (size_t)(bn0 + r) * ldb + kko + ssub;
  }
  unsigned char* dstA = lds + wid * 1024;           // + j*4096
  unsigned char* dstB = lds + 16384 + wid * 1024;   // + j*4096

  f32x4 acc[4][4] = {};
  const int nkt = K >> 6;
  for (int kt = 0; kt < nkt; ++kt) {
    const int kc = kt << 6;
#pragma unroll
    for (int j = 0; j < 4; ++j) {
      gl_lds16(A + aoff[j] + kc, dstA + j * 4096);
      gl_lds16(B + boff[j] + kc, dstB + j * 4096);
    }
    __syncthreads();

#pragma unroll
    for (int kk = 0; kk < 2; ++kk) {
      bf16x8 af[4], bg[4];
#pragma unroll
      for (int mi = 0; mi < 4; ++mi)
        af[mi] = *(const bf16x8*)(lds + kk * 8192 + (wr * 64 + mi * 16 + l15) * 64 + kq * 16);
#pragma unroll
      for (int ni = 0; ni < 4; ++ni)
        bg[ni] = *(const bf16x8*)(lds + 16384 + kk * 8192 + (wc * 64 + ni * 16 + l15) * 64 + kq * 16);
#pragma unroll
      for (int mi = 0; mi < 4; ++mi)
#pragma unroll
        for (int ni = 0; ni < 4; ++ni)
          acc[mi][ni] = __builtin_amdgcn_mfma_f32_16x16x32_bf16(af[mi], bg[ni], acc[mi][ni], 0, 0, 0);
    }
    __syncthreads();
  }

  // epilogue: C/D layout col = lane&15, row = (lane>>4)*4 + reg
  if constexpr (MODE == 4) {
    __shared__ float redsm[128][2];
    unsigned short* pp = (unsigned short*)Cv + (size_t)blockIdx.z * cstride;
    float rs[4][4];
#pragma unroll
    for (int mi = 0; mi < 4; ++mi)
#pragma unroll
      for (int r = 0; r < 4; ++r) rs[mi][r] = 0.f;
#pragma unroll
    for (int mi = 0; mi < 4; ++mi)
#pragma unroll
      for (int ni = 0; ni < 4; ++ni)
#pragma unroll
        for (int r = 0; r < 4; ++r) {
          const float e = exp2f(acc[mi][ni][r] * 0.045084220027780106f);  // exp(acc/32)
          rs[mi][r] += e;
          const int row = bm0 + wr * 64 + mi * 16 + kq * 4 + r;
          const int col = bn0 + wc * 64 + ni * 16 + l15;
          pp[(size_t)row * ldc + col] = f2bf(e);
        }
#pragma unroll
    for (int mi = 0; mi < 4; ++mi)
#pragma unroll
      for (int r = 0; r < 4; ++r) {
        float s = rs[mi][r];
        s += __shfl_xor(s, 1); s += __shfl_xor(s, 2);
        s += __shfl_xor(s, 4); s += __shfl_xor(s, 8);
        rs[mi][r] = s;
      }
    if (l15 == 0) {
#pragma unroll
      for (int mi = 0; mi < 4; ++mi)
#pragma unroll
        for (int r = 0; r < 4; ++r)
          redsm[wr * 64 + mi * 16 + kq * 4 + r][wc] = rs[mi][r];
    }
    __syncthreads();
    if (tid < 128)
      aux[((size_t)blockIdx.z * 16 + tx) * 2048 + bm0 + tid] =
          redsm[tid][0] + redsm[tid][1];
  } else {  // MODE 5
    float* op = (float*)Cv + (size_t)blockIdx.z * cstride;
#pragma unroll
    for (int mi = 0; mi < 4; ++mi)
#pragma unroll
      for (int r = 0; r < 4; ++r) {
        const int row = bm0 + wr * 64 + mi * 16 + kq * 4 + r;
        const float iv = smInv[wr * 64 + mi * 16 + kq * 4 + r];
#pragma unroll
        for (int ni = 0; ni < 4; ++ni) {
          const int col = bn0 + wc * 64 + ni * 16 + l15;
          op[(size_t)row * ldc + col] = acc[mi][ni][r] * iv;
        }
      }
  }
}

// ---------- launch ----------
extern "C" void kernel_launch(void* const* d_in, const int* in_sizes, int n_in,
                              void* d_out, int out_size, void* d_ws, size_t ws_size,
                              hipStream_t stream) {
  const float* x  = (const float*)d_in[0];
  const float* Wq = (const float*)d_in[1];
  const float* Wk = (const float*)d_in[2];
  const float* Wv = (const float*)d_in[3];
  float* out = (float*)d_out;
  char* ws = (char*)d_ws;

  // workspace layout (bytes)
  unsigned short* xb     = (unsigned short*)ws;                  // 33.5 MB (dead after QKV)
  unsigned short* wt_all = (unsigned short*)(ws + 33554432);     // 6 MB: WqT|WkT|WvT [3072][1024]
  unsigned short* qb     = (unsigned short*)(ws + 39845888);     // 33.5 MB
  unsigned short* kb     = qb + 16777216;                        // 33.5 MB
  unsigned short* vt     = kb + 16777216;                        // 33.5 MB (vT: [b*1024+e][s])
  const size_t off_scores = 140509184ull;                        // end of vt

  // per-batch attention scratch: P' bf16 8 MiB + partials 128 KiB
  const size_t per_b = 8388608ull + 131072ull;
  int G; char *pPc, *partc;
  const size_t avail = ws_size > off_scores ? ws_size - off_scores : 0;
  G = (int)(avail / per_b); if (G > 8) G = 8;
  if (G >= 1) {
    pPc   = ws + off_scores;
    partc = pPc + (size_t)G * 8388608ull;
  } else {
    G = 2;  // fallback: reuse xb region (33.5 MB >= 2 x 8.53 MB); xb dead after QKV
    pPc   = ws;
    partc = ws + 2 * 8388608ull;
  }

  cast_f32_bf16<<<2048, 256, 0, stream>>>(x, xb, 16384 * 1024);
  transpose_cast_w3<<<dim3(64, 64, 3), 256, 0, stream>>>(Wq, Wk, Wv, wt_all);

  // fused QKV projection: M=16384, N=3072, K=1024 -- 256^2 tile, 768 blocks
  gemm256s<<<dim3(12, 64), 512, 0, stream>>>(xb, 1024, wt_all, 1024, 1024, qb);

  for (int b0 = 0; b0 < 8; b0 += G) {
    const int g = (8 - b0) < G ? (8 - b0) : G;
    const size_t so = (size_t)b0 * 2097152;  // q/k/v/out batch offset (elems)
    // P' = exp(q.k^T/32) bf16 + partial row sums: M=N=2048, K=1024
    gemm_bt<4><<<dim3(16, 16, g), 256, 0, stream>>>(
        qb + so, 1024, 2097152, kb + so, 1024, 2097152, 1024,
        (unsigned short*)pPc, 2048, 4194304, (float*)partc);
    // out = (P'.v) * inv : A=P' [2048][2048] bf16, B^T = vT_b [1024][2048], K=2048
    // (inv computed in-block from the 16 partials; combine kernel folded away)
    gemm_bt<5><<<dim3(8, 16, g), 256, 0, stream>>>(
        (const unsigned short*)pPc, 2048, 4194304,
        vt + so, 2048, 2097152, 2048,
        out + so, 1024, 2097152, (float*)partc);
  }
}

// Round 11
// 352.215 us; speedup vs baseline: 1.0434x; 1.0293x over previous
//
#include <hip/hip_runtime.h>
#include <hip/hip_bf16.h>

typedef __bf16 bf16x8 __attribute__((ext_vector_type(8)));
typedef float  f32x4  __attribute__((ext_vector_type(4)));

// ---------- helpers ----------
static __device__ __forceinline__ unsigned short f2bf(float f) {
  unsigned int u = __float_as_uint(f);
  u += 0x7FFFu + ((u >> 16) & 1u);   // round-to-nearest-even
  return (unsigned short)(u >> 16);
}

static __device__ __forceinline__ void gl_lds16(const void* g, void* l) {
  __builtin_amdgcn_global_load_lds(
      (const __attribute__((address_space(1))) void*)g,
      (__attribute__((address_space(3))) void*)l,
      16, 0, 0);
}

// ---------- cast x: f32 -> bf16 ----------
__global__ __launch_bounds__(256) void cast_f32_bf16(
    const float* __restrict__ in, unsigned short* __restrict__ out, int n) {
  int i = (blockIdx.x * 256 + threadIdx.x) * 4;
  const int stride = gridDim.x * 256 * 4;
  for (; i < n; i += stride) {
    float4 f = *(const float4*)(in + i);
    ushort4 o;
    o.x = f2bf(f.x); o.y = f2bf(f.y); o.z = f2bf(f.z); o.w = f2bf(f.w);
    *(ushort4*)(out + i) = o;
  }
}

// ---------- transpose-cast Wq|Wk|Wv in one launch (z picks the matrix) ----------
__global__ __launch_bounds__(256) void transpose_cast_w3(
    const float* __restrict__ w0, const float* __restrict__ w1,
    const float* __restrict__ w2, unsigned short* __restrict__ wt) {
  __shared__ float tile[16][17];
  const float* w = blockIdx.z == 0 ? w0 : (blockIdx.z == 1 ? w1 : w2);
  unsigned short* o = wt + (size_t)blockIdx.z * 1048576;
  const int tx = threadIdx.x & 15, ty = threadIdx.x >> 4;
  const int bx = blockIdx.x * 16, by = blockIdx.y * 16;
  tile[ty][tx] = w[(size_t)(by + ty) * 1024 + bx + tx];
  __syncthreads();
  o[(size_t)(bx + ty) * 1024 + by + tx] = f2bf(tile[tx][ty]);
}

// ---------- 128x128-tile bf16 MFMA GEMM, BK=64 single buffer (r7 = measured best) ----------
// B given transposed ([N][K]). XCD-locality remap: d2 -> (ty=d2%gy, tx=d2/gy);
// gy%8==0 keeps A-row-panel sharers on one XCD. blockIdx.z batches.
// LDS 32 KiB: A 16K as [kk 0..1][row 0..127][32e=64B], B same. Staging = 16
// consecutive rows x 64 B contiguous per wave-load (full cache lines); LDS
// dest linear. Scorecard (QKV dispatch): r2 175 / r7 164* / r8-dbuf 183 /
// r9-tbuf 175 / r10-256sq 240 -- this structure is the keeper.
// MODE 3: fused-QKV split write (Cv = qb base; kb = +16Mi elems, vt = +32Mi)
// MODE 4: scores + fused exp + per-block partial row-sums -> aux[(z*16+tx)*2048+row]
// MODE 5: PV; inv computed IN-BLOCK from the 16 partials (combine kernel folded)
template <int MODE>
__global__ __launch_bounds__(256, 2) void gemm_bt(
    const unsigned short* __restrict__ A, int lda, size_t astride,
    const unsigned short* __restrict__ B, int ldb, size_t bstride,
    int K, void* __restrict__ Cv, int ldc, size_t cstride,
    float* __restrict__ aux) {
  __shared__ __align__(16) unsigned char lds[32768];  // A 16K | B 16K
  __shared__ float smInv[128];
  const unsigned d2 = blockIdx.x + gridDim.x * blockIdx.y;
  const unsigned ty = d2 % gridDim.y;
  const unsigned tx = d2 / gridDim.y;
  const int bn0 = tx * 128;
  const int bm0 = ty * 128;
  A += (size_t)blockIdx.z * astride;
  B += (size_t)blockIdx.z * bstride;

  const int tid = threadIdx.x;
  const int wid = tid >> 6, lane = tid & 63;
  const int wr = wid >> 1, wc = wid & 1;
  const int l15 = lane & 15, kq = lane >> 4;

  if constexpr (MODE == 5) {  // inv[row] for this block's 128 rows
    if (tid < 128) {
      const float* p = aux + (size_t)blockIdx.z * 32768 + bm0 + tid;
      float s = 0.f;
#pragma unroll
      for (int j = 0; j < 16; ++j) s += p[j * 2048];
      smInv[tid] = 1.0f / s;   // visible after iter-0 __syncthreads
    }
  }

  // staging: chunk c = j*256 + tid -> kk = j>>1, row = (j&1)*64 + tid>>2, sub = tid&3
  const int sr = tid >> 2;
  const int ssub = (tid & 3) * 8;
  size_t aoff[4], boff[4];
#pragma unroll
  for (int j = 0; j < 4; ++j) {
    const int r = (j & 1) * 64 + sr;
    const int kko = (j >> 1) * 32;
    aoff[j] = (size_t)(bm0 + r) * lda + kko + ssub;
    boff[j] = (size_t)(bn0 + r) * ldb + kko + ssub;
  }
  unsigned char* dstA = lds + wid * 1024;           // + j*4096
  unsigned char* dstB = lds + 16384 + wid * 1024;   // + j*4096

  f32x4 acc[4][4] = {};
  const int nkt = K >> 6;
  for (int kt = 0; kt < nkt; ++kt) {
    const int kc = kt << 6;
#pragma unroll
    for (int j = 0; j < 4; ++j) {
      gl_lds16(A + aoff[j] + kc, dstA + j * 4096);
      gl_lds16(B + boff[j] + kc, dstB + j * 4096);
    }
    __syncthreads();

#pragma unroll
    for (int kk = 0; kk < 2; ++kk) {
      bf16x8 af[4], bg[4];
#pragma unroll
      for (int mi = 0; mi < 4; ++mi)
        af[mi] = *(const bf16x8*)(lds + kk * 8192 + (wr * 64 + mi * 16 + l15) * 64 + kq * 16);
#pragma unroll
      for (int ni = 0; ni < 4; ++ni)
        bg[ni] = *(const bf16x8*)(lds + 16384 + kk * 8192 + (wc * 64 + ni * 16 + l15) * 64 + kq * 16);
#pragma unroll
      for (int mi = 0; mi < 4; ++mi)
#pragma unroll
        for (int ni = 0; ni < 4; ++ni)
          acc[mi][ni] = __builtin_amdgcn_mfma_f32_16x16x32_bf16(af[mi], bg[ni], acc[mi][ni], 0, 0, 0);
    }
    __syncthreads();
  }

  // epilogue: C/D layout col = lane&15, row = (lane>>4)*4 + reg  [verified m89/m91]
  if constexpr (MODE == 3) {
#pragma unroll
    for (int mi = 0; mi < 4; ++mi)
#pragma unroll
      for (int ni = 0; ni < 4; ++ni)
#pragma unroll
        for (int r = 0; r < 4; ++r) {
          const int row = bm0 + wr * 64 + mi * 16 + kq * 4 + r;
          const int col = bn0 + wc * 64 + ni * 16 + l15;
          const float v = acc[mi][ni][r];
          unsigned short* q = (unsigned short*)Cv;
          if (col < 1024) {
            q[(size_t)row * 1024 + col] = f2bf(v);
          } else if (col < 2048) {
            q[16777216u + (size_t)row * 1024 + (col - 1024)] = f2bf(v);
          } else {
            const int b = row >> 11, s = row & 2047;
            q[33554432u + ((size_t)(b * 1024 + (col - 2048))) * 2048 + s] = f2bf(v);
          }
        }
  } else if constexpr (MODE == 4) {
    __shared__ float redsm[128][2];
    unsigned short* pp = (unsigned short*)Cv + (size_t)blockIdx.z * cstride;
    float rs[4][4];
#pragma unroll
    for (int mi = 0; mi < 4; ++mi)
#pragma unroll
      for (int r = 0; r < 4; ++r) rs[mi][r] = 0.f;
#pragma unroll
    for (int mi = 0; mi < 4; ++mi)
#pragma unroll
      for (int ni = 0; ni < 4; ++ni)
#pragma unroll
        for (int r = 0; r < 4; ++r) {
          const float e = exp2f(acc[mi][ni][r] * 0.045084220027780106f);  // exp(acc/32)
          rs[mi][r] += e;
          const int row = bm0 + wr * 64 + mi * 16 + kq * 4 + r;
          const int col = bn0 + wc * 64 + ni * 16 + l15;
          pp[(size_t)row * ldc + col] = f2bf(e);
        }
#pragma unroll
    for (int mi = 0; mi < 4; ++mi)
#pragma unroll
      for (int r = 0; r < 4; ++r) {
        float s = rs[mi][r];
        s += __shfl_xor(s, 1); s += __shfl_xor(s, 2);
        s += __shfl_xor(s, 4); s += __shfl_xor(s, 8);
        rs[mi][r] = s;
      }
    if (l15 == 0) {
#pragma unroll
      for (int mi = 0; mi < 4; ++mi)
#pragma unroll
        for (int r = 0; r < 4; ++r)
          redsm[wr * 64 + mi * 16 + kq * 4 + r][wc] = rs[mi][r];
    }
    __syncthreads();
    if (tid < 128)
      aux[((size_t)blockIdx.z * 16 + tx) * 2048 + bm0 + tid] =
          redsm[tid][0] + redsm[tid][1];
  } else {  // MODE 5
    float* op = (float*)Cv + (size_t)blockIdx.z * cstride;
#pragma unroll
    for (int mi = 0; mi < 4; ++mi)
#pragma unroll
      for (int r = 0; r < 4; ++r) {
        const int row = bm0 + wr * 64 + mi * 16 + kq * 4 + r;
        const float iv = smInv[wr * 64 + mi * 16 + kq * 4 + r];
#pragma unroll
        for (int ni = 0; ni < 4; ++ni) {
          const int col = bn0 + wc * 64 + ni * 16 + l15;
          op[(size_t)row * ldc + col] = acc[mi][ni][r] * iv;
        }
      }
  }
}

// ---------- launch ----------
extern "C" void kernel_launch(void* const* d_in, const int* in_sizes, int n_in,
                              void* d_out, int out_size, void* d_ws, size_t ws_size,
                              hipStream_t stream) {
  const float* x  = (const float*)d_in[0];
  const float* Wq = (const float*)d_in[1];
  const float* Wk = (const float*)d_in[2];
  const float* Wv = (const float*)d_in[3];
  float* out = (float*)d_out;
  char* ws = (char*)d_ws;

  // workspace layout (bytes)
  unsigned short* xb     = (unsigned short*)ws;                  // 33.5 MB (dead after QKV)
  unsigned short* wt_all = (unsigned short*)(ws + 33554432);     // 6 MB: WqT|WkT|WvT [3072][1024]
  unsigned short* qb     = (unsigned short*)(ws + 39845888);     // 33.5 MB
  unsigned short* kb     = qb + 16777216;                        // 33.5 MB
  unsigned short* vt     = kb + 16777216;                        // 33.5 MB (vT: [b*1024+e][s])
  const size_t off_scores = 140509184ull;                        // end of vt

  // per-batch attention scratch: P' bf16 8 MiB + partials 128 KiB
  const size_t per_b = 8388608ull + 131072ull;
  int G; char *pPc, *partc;
  const size_t avail = ws_size > off_scores ? ws_size - off_scores : 0;
  G = (int)(avail / per_b); if (G > 8) G = 8;
  if (G >= 1) {
    pPc   = ws + off_scores;
    partc = pPc + (size_t)G * 8388608ull;
  } else {
    G = 2;  // fallback: reuse xb region (33.5 MB >= 2 x 8.53 MB); xb dead after QKV
    pPc   = ws;
    partc = ws + 2 * 8388608ull;
  }

  cast_f32_bf16<<<2048, 256, 0, stream>>>(x, xb, 16384 * 1024);
  transpose_cast_w3<<<dim3(64, 64, 3), 256, 0, stream>>>(Wq, Wk, Wv, wt_all);

  // fused QKV projection: M=16384, N=3072, K=1024 -- 128^2 tile (r7 structure)
  gemm_bt<3><<<dim3(24, 128), 256, 0, stream>>>(xb, 1024, 0, wt_all, 1024, 0,
                                                1024, qb, 0, 0, nullptr);

  for (int b0 = 0; b0 < 8; b0 += G) {
    const int g = (8 - b0) < G ? (8 - b0) : G;
    const size_t so = (size_t)b0 * 2097152;  // q/k/v/out batch offset (elems)
    // P' = exp(q.k^T/32) bf16 + partial row sums: M=N=2048, K=1024
    gemm_bt<4><<<dim3(16, 16, g), 256, 0, stream>>>(
        qb + so, 1024, 2097152, kb + so, 1024, 2097152, 1024,
        (unsigned short*)pPc, 2048, 4194304, (float*)partc);
    // out = (P'.v) * inv : A=P' [2048][2048] bf16, B^T = vT_b [1024][2048], K=2048
    // (inv computed in-block from the 16 partials; combine kernel folded away)
    gemm_bt<5><<<dim3(8, 16, g), 256, 0, stream>>>(
        (const unsigned short*)pPc, 2048, 4194304,
        vt + so, 2048, 2097152, 2048,
        out + so, 1024, 2097152, (float*)partc);
  }
}